// Round 3
// baseline (3778.785 us; speedup 1.0000x reference)
//
#include <hip/hip_runtime.h>
#include <math.h>

#define HB 8
#define TT 1024
#define NSTATE 16
#define NTT 6
#define NMM 8
#define MM (HB*TT)   /* 8192 rows */
#define EPSV 1e-5f
#define CHUNK 64
#define NCH (TT/CHUNK)   /* 16 */
#define AKS 128          /* attention keys staged per block iter */
#define VSTR 132         /* V-transpose LDS stride (halves) */

typedef _Float16 f16x8 __attribute__((ext_vector_type(8)));
typedef _Float16 f16x4 __attribute__((ext_vector_type(4)));
typedef float f32x4_t __attribute__((ext_vector_type(4)));

static __device__ __forceinline__ void split8(const float4 a, const float4 b,
                                              f16x8& h, f16x8& l)
{
  float x[8] = {a.x, a.y, a.z, a.w, b.x, b.y, b.z, b.w};
#pragma unroll
  for (int i = 0; i < 8; i++) {
    _Float16 hi = (_Float16)x[i];
    h[i] = hi;
    l[i] = (_Float16)(x[i] - (float)hi);
  }
}

// async global->LDS, 16B per lane; LDS dest must be wave-uniform base.
static __device__ __forceinline__ void gload16(const _Float16* g, _Float16* l)
{
  __builtin_amdgcn_global_load_lds(
      (const __attribute__((address_space(1))) unsigned int*)g,
      (__attribute__((address_space(3))) unsigned int*)l, 16, 0, 0);
}

// ---------------------------------------------------------------------------
// Split layout: matrix [rows x K] fp32 -> [K/32 segs][rows][64 halves].
// Each 128B row-seg: 8 units of 16B. Source col group g (8 cols) stores
// hi at unit (g ^ (row&7)), lo at that ^4. XOR swizzle is baked into global
// so linear global_load_lds staging lands swizzled; ds_read_b128 fragment
// reads (unit = quad ^ (row&7)) are then exactly 8 lanes/bank-group = free.
// ---------------------------------------------------------------------------
static __device__ __forceinline__ void store_split(_Float16* __restrict__ dst,
                                                   size_t row, int col, float v)
{
  const int cc = col & 31;
  const size_t o = ((size_t)(col >> 5) * MM + row) * 64
                 + (size_t)(((((cc >> 3) ^ ((int)row & 7)) * 8)) + (cc & 7));
  _Float16 hi = (_Float16)v;
  dst[o] = hi;
  dst[o ^ (size_t)32] = (_Float16)(v - (float)hi);
}

static __device__ __forceinline__ void split_item(
    const float* __restrict__ src, int lda, int rows,
    _Float16* __restrict__ dst, int item)
{
  const int m = item % rows;
  const int seg = item / rows;
  const float* s = src + (size_t)m * lda + seg * 32;
  _Float16* d = dst + (size_t)item * 64;
  const int swz = m & 7;
#pragma unroll
  for (int g = 0; g < 4; g++) {
    float4 x0 = *(const float4*)&s[g * 8];
    float4 x1 = *(const float4*)&s[g * 8 + 4];
    f16x8 h, l;
    split8(x0, x1, h, l);
    const int u = (g ^ swz) * 8;
    *(f16x8*)&d[u] = h;
    *(f16x8*)&d[u ^ 32] = l;
  }
}

__global__ __launch_bounds__(256) void split_k(
    const float* __restrict__ src, int lda, int rows,
    _Float16* __restrict__ dst)
{
  split_item(src, lda, rows, dst, blockIdx.x * 256 + threadIdx.x);
}

// fused 3-region split (per mamba layer: inproj / xproj / dtw weights)
__global__ __launch_bounds__(256) void split3_k(
    const float* __restrict__ s0, int lda0, int rows0, _Float16* __restrict__ d0, int nb0,
    const float* __restrict__ s1, int lda1, int rows1, _Float16* __restrict__ d1, int nb1,
    const float* __restrict__ s2, int lda2, int rows2, _Float16* __restrict__ d2)
{
  const int bid = blockIdx.x;
  if (bid < nb0) {
    split_item(s0, lda0, rows0, d0, bid * 256 + threadIdx.x);
  } else if (bid < nb0 + nb1) {
    split_item(s1, lda1, rows1, d1, (bid - nb0) * 256 + threadIdx.x);
  } else {
    split_item(s2, lda2, rows2, d2, (bid - nb0 - nb1) * 256 + threadIdx.x);
  }
}

// ---------------------------------------------------------------------------
// fp16x3 split-precision MFMA GEMM on pre-split operands.
// A: [K/32][MM][64] halves (astr=MM rows/seg), W: [K/32][wstr][64] halves.
// Tile 128xTN, BK=32 (one seg per K-step), global_load_lds staging.
// S>1: fp32 partials to P. S==1 && Cs: split-format output (bias/act applied).
// ---------------------------------------------------------------------------
template<int TN>
__global__ __launch_bounds__(256, 4) void gemm_ps_t(
    const _Float16* __restrict__ Ap, int astr,
    const _Float16* __restrict__ Wp, int wstr,
    const float* __restrict__ bias,
    float* __restrict__ C,
    float* __restrict__ P,
    _Float16* __restrict__ Cs,
    int N, int K, int S, int act)
{
  __shared__ __align__(16) _Float16 As[128 * 64];
  __shared__ __align__(16) _Float16 Bs[TN * 64];
  const int tid = threadIdx.x;
  const int lane = tid & 63;
  const int w = tid >> 6;
  const int quad = lane >> 4;
  const int l16 = lane & 15;
  const int m0 = blockIdx.y * 128;
  const int n0 = blockIdx.x * TN;
  const int z = blockIdx.z;
  const int nseg = K / 32;
  const int segb = z * (nseg / S);
  const int sege = segb + nseg / S;

  constexpr int MI = (TN == 128) ? 4 : 2;
  const int w0 = (TN == 128) ? (w & 1) : w;
  const int w1 = (TN == 128) ? (w >> 1) : 0;
  const int rowbase = (TN == 128) ? w0 * 64 : w0 * 32;

  f32x4_t acc[MI][4];
#pragma unroll
  for (int i = 0; i < MI; i++)
#pragma unroll
    for (int j = 0; j < 4; j++)
#pragma unroll
      for (int r = 0; r < 4; r++) acc[i][j][r] = 0.f;

  const int sw8 = (quad ^ (l16 & 7)) * 8;                 // hi unit offset
  const int abase = (rowbase + l16) * 64 + sw8;
  const int bbase = (w1 * 64 + l16) * 64 + sw8;
  const int wave64 = tid & 192;                            // wave*64

  for (int seg = segb; seg < sege; seg++) {
    const _Float16* At = Ap + ((size_t)seg * astr + m0) * 64;
    const _Float16* Bt = Wp + ((size_t)seg * wstr + n0) * 64;
    __syncthreads();
#pragma unroll
    for (int j = 0; j < 4; j++)
      gload16(At + (size_t)(j * 256 + tid) * 8, &As[(j * 256 + wave64) * 8]);
#pragma unroll
    for (int j = 0; j < TN / 32; j++)
      gload16(Bt + (size_t)(j * 256 + tid) * 8, &Bs[(j * 256 + wave64) * 8]);
    __syncthreads();   // compiler emits vmcnt(0)+lgkmcnt(0) drain here

    f16x8 bh[4], bl[4];
#pragma unroll
    for (int ni = 0; ni < 4; ni++) {
      bh[ni] = *(const f16x8*)&Bs[bbase + ni * 1024];
      bl[ni] = *(const f16x8*)&Bs[(bbase ^ 32) + ni * 1024];
    }
#pragma unroll
    for (int mi = 0; mi < MI; mi++) {
      f16x8 ah = *(const f16x8*)&As[abase + mi * 1024];
      f16x8 al = *(const f16x8*)&As[(abase ^ 32) + mi * 1024];
#pragma unroll
      for (int ni = 0; ni < 4; ni++) {
        acc[mi][ni] = __builtin_amdgcn_mfma_f32_16x16x32_f16(ah, bh[ni], acc[mi][ni], 0, 0, 0);
        acc[mi][ni] = __builtin_amdgcn_mfma_f32_16x16x32_f16(ah, bl[ni], acc[mi][ni], 0, 0, 0);
        acc[mi][ni] = __builtin_amdgcn_mfma_f32_16x16x32_f16(al, bh[ni], acc[mi][ni], 0, 0, 0);
      }
    }
  }

  float* dst = (S == 1) ? C : (P + (size_t)z * MM * N);
#pragma unroll
  for (int ni = 0; ni < 4; ni++) {
    const int n = n0 + w1 * 64 + ni * 16 + l16;
    const float bv = (S == 1 && bias) ? bias[n] : 0.f;
#pragma unroll
    for (int mi = 0; mi < MI; mi++) {
      const int mbase = m0 + rowbase + mi * 16 + quad * 4;
#pragma unroll
      for (int r = 0; r < 4; r++) {
        float v = acc[mi][ni][r] + bv;
        if (S == 1) {
          if (act == 1) v = fmaxf(v, 0.f);
          else if (act == 2) v = fmaxf(v, 0.f) + log1pf(__expf(-fabsf(v)));
        }
        const int row = mbase + r;
        if (S == 1 && Cs) {
          store_split(Cs, (size_t)row, n, v);
        } else {
          dst[(size_t)row * N + n] = v;
        }
      }
    }
  }
}

// ---------------------------------------------------------------------------
// Split-K reduce: C(or split Cs) = act( sum_z P[z] + bias ).
// Optional dta: also emit split of cols 0..31 (dt_r for the dtw GEMM).
// ---------------------------------------------------------------------------
__global__ __launch_bounds__(256) void reduce_k(
    const float* __restrict__ P, const float* __restrict__ bias,
    float* __restrict__ C, _Float16* __restrict__ Cs,
    _Float16* __restrict__ dta,
    int nmask, int nshift, int S, int act, int stride4)
{
  const int idx = blockIdx.x * 256 + threadIdx.x;
  float4 a = *(const float4*)&P[(size_t)idx * 4];
  for (int z = 1; z < S; z++) {
    float4 p = *(const float4*)&P[(size_t)(idx + (size_t)z * stride4) * 4];
    a.x += p.x; a.y += p.y; a.z += p.z; a.w += p.w;
  }
  if (bias) {
    float4 bv = *(const float4*)&bias[(idx * 4) & nmask];
    a.x += bv.x; a.y += bv.y; a.z += bv.z; a.w += bv.w;
  }
  if (act == 1) {
    a.x = fmaxf(a.x, 0.f); a.y = fmaxf(a.y, 0.f);
    a.z = fmaxf(a.z, 0.f); a.w = fmaxf(a.w, 0.f);
  } else if (act == 2) {
    a.x = fmaxf(a.x, 0.f) + log1pf(__expf(-fabsf(a.x)));
    a.y = fmaxf(a.y, 0.f) + log1pf(__expf(-fabsf(a.y)));
    a.z = fmaxf(a.z, 0.f) + log1pf(__expf(-fabsf(a.z)));
    a.w = fmaxf(a.w, 0.f) + log1pf(__expf(-fabsf(a.w)));
  }
  const int c0 = (idx * 4) & nmask;
  const size_t row = (size_t)(idx * 4) >> nshift;
  if (Cs) {
    store_split(Cs, row, c0,     a.x);
    store_split(Cs, row, c0 + 1, a.y);
    store_split(Cs, row, c0 + 2, a.z);
    store_split(Cs, row, c0 + 3, a.w);
  } else {
    *(float4*)&C[(size_t)idx * 4] = a;
  }
  if (dta && c0 < 32) {
    store_split(dta, row, c0,     a.x);
    store_split(dta, row, c0 + 1, a.y);
    store_split(dta, row, c0 + 2, a.z);
    store_split(dta, row, c0 + 3, a.w);
  }
}

// ---------------------------------------------------------------------------
// MFMA flash attention (no-max softmax), writes SPLIT-format output (the
// only consumer is the wo GEMM). Values identical to fp32-then-split.
// ---------------------------------------------------------------------------
__global__ __launch_bounds__(256) void attn_mfma_k(
    const float* __restrict__ qkv, _Float16* __restrict__ os)
{
  __shared__ _Float16 Khi[AKS * 16], Klo[AKS * 16];
  __shared__ _Float16 Vthi[16 * VSTR], Vtlo[16 * VSTR];
  __shared__ float Pscr[4][16 * 18];

  const int tid = threadIdx.x;
  const int lane = tid & 63;
  const int wv = tid >> 6;
  const int quad = lane >> 4;
  const int l16 = lane & 15;
  const int qh = quad & 1;
  const int bh = blockIdx.y;
  const int b = bh >> 3;
  const int h = bh & 7;
  const int qb0 = blockIdx.x * 128;

  f16x8 qa[2];
#pragma unroll
  for (int u = 0; u < 2; u++) {
    const int qrow = qb0 + wv * 32 + u * 16 + l16;
    const float* qp = qkv + (size_t)(b * TT + qrow) * 384 + h * 16 + qh * 8;
    float4 x0 = *(const float4*)&qp[0];
    float4 x1 = *(const float4*)&qp[4];
    float xv[8] = {x0.x, x0.y, x0.z, x0.w, x1.x, x1.y, x1.z, x1.w};
#pragma unroll
    for (int j = 0; j < 8; j++) {
      float q = xv[j] * 0.25f;
      _Float16 hi = (_Float16)q;
      _Float16 lo = (_Float16)(q - (float)hi);
      qa[u][j] = (quad < 2) ? hi : lo;
    }
  }

  f32x4_t oacc[2];
  float lacc[2][4];
#pragma unroll
  for (int u = 0; u < 2; u++)
#pragma unroll
    for (int r = 0; r < 4; r++) { oacc[u][r] = 0.f; lacc[u][r] = 0.f; }

  float* Pw = &Pscr[wv][0];

  for (int ks = 0; ks < TT; ks += AKS) {
    __syncthreads();
    {
      const int key = tid >> 1, hf = tid & 1;
      const float* kp = qkv + (size_t)(b * TT + ks + key) * 384 + 128 + h * 16 + hf * 8;
      float4 k0 = *(const float4*)&kp[0];
      float4 k1 = *(const float4*)&kp[4];
      f16x8 vh, vl;
      split8(k0, k1, vh, vl);
      *(f16x8*)&Khi[key * 16 + hf * 8] = vh;
      *(f16x8*)&Klo[key * 16 + hf * 8] = vl;
      const float* vp = kp + 128;
      float4 v0 = *(const float4*)&vp[0];
      float4 v1 = *(const float4*)&vp[4];
      float vvv[8] = {v0.x, v0.y, v0.z, v0.w, v1.x, v1.y, v1.z, v1.w};
#pragma unroll
      for (int j = 0; j < 8; j++) {
        const int d = hf * 8 + j;
        _Float16 hi = (_Float16)vvv[j];
        Vthi[d * VSTR + key] = hi;
        Vtlo[d * VSTR + key] = (_Float16)(vvv[j] - (float)hi);
      }
    }
    __syncthreads();

    for (int kt = 0; kt < AKS; kt += 16) {
      f16x8 kfh = *(const f16x8*)&Khi[(kt + l16) * 16 + qh * 8];
      f16x8 kfl = *(const f16x8*)&Klo[(kt + l16) * 16 + qh * 8];
      const int vo = l16 * VSTR + kt + qh * 8;
      f16x4 va0 = *(const f16x4*)&Vthi[vo];
      f16x4 va1 = *(const f16x4*)&Vthi[vo + 4];
      f16x4 vb0 = *(const f16x4*)&Vtlo[vo];
      f16x4 vb1 = *(const f16x4*)&Vtlo[vo + 4];
      f16x8 vfh, vfl;
#pragma unroll
      for (int i = 0; i < 4; i++) {
        vfh[i] = va0[i]; vfh[4 + i] = va1[i];
        vfl[i] = vb0[i]; vfl[4 + i] = vb1[i];
      }

#pragma unroll
      for (int u = 0; u < 2; u++) {
        f32x4_t s;
#pragma unroll
        for (int r = 0; r < 4; r++) s[r] = 0.f;
        s = __builtin_amdgcn_mfma_f32_16x16x32_f16(qa[u], kfh, s, 0, 0, 0);
        s = __builtin_amdgcn_mfma_f32_16x16x32_f16(qa[u], kfl, s, 0, 0, 0);
        float p[4];
#pragma unroll
        for (int r = 0; r < 4; r++) {
          p[r] = __expf(s[r]);
          lacc[u][r] += p[r];
        }
        float* ps = Pw + (quad * 4) * 18 + l16;
        ps[0] = p[0]; ps[18] = p[1]; ps[36] = p[2]; ps[54] = p[3];
        __asm__ volatile("s_waitcnt lgkmcnt(0)" ::: "memory");
        const float* pr = Pw + l16 * 18 + qh * 8;
        f16x8 pa;
#pragma unroll
        for (int j = 0; j < 8; j++) {
          float pv = pr[j];
          _Float16 hi = (_Float16)pv;
          _Float16 lo = (_Float16)(pv - (float)hi);
          pa[j] = (quad < 2) ? hi : lo;
        }
        oacc[u] = __builtin_amdgcn_mfma_f32_16x16x32_f16(pa, vfh, oacc[u], 0, 0, 0);
        oacc[u] = __builtin_amdgcn_mfma_f32_16x16x32_f16(pa, vfl, oacc[u], 0, 0, 0);
        __asm__ volatile("s_waitcnt lgkmcnt(0)" ::: "memory");
      }
    }
  }

#pragma unroll
  for (int u = 0; u < 2; u++) {
#pragma unroll
    for (int r = 0; r < 4; r++) {
      float lv = lacc[u][r];
      lv += __shfl_xor(lv, 1);
      lv += __shfl_xor(lv, 2);
      lv += __shfl_xor(lv, 4);
      lv += __shfl_xor(lv, 8);
      const float inv = 1.f / lv;
      const int qrow = qb0 + wv * 32 + u * 16 + quad * 4 + r;
      const size_t m = (size_t)(b * TT + qrow);
      store_split(os, m, h * 16 + l16, oacc[u][r] * inv);
    }
  }
}

// ---------------------------------------------------------------------------
// out = LN(a + bvec) * w + bb  (fp32 out + fused split out)
// ---------------------------------------------------------------------------
__global__ __launch_bounds__(256) void add_ln_k(
    const float* __restrict__ a, const float* __restrict__ bvec,
    const float* __restrict__ w, const float* __restrict__ bb,
    float* __restrict__ out, _Float16* __restrict__ outs)
{
  const int tid = threadIdx.x;
  const int wave = tid >> 6, lane = tid & 63;
  const size_t row = (size_t)blockIdx.x * 4 + wave;
  const float* pa = a + row * 128;
  const float* pb = bvec + row * 128;
  float v0 = pa[lane] + pb[lane];
  float v1 = pa[lane + 64] + pb[lane + 64];
  float s1 = v0 + v1, s2 = v0 * v0 + v1 * v1;
#pragma unroll
  for (int off = 32; off; off >>= 1) {
    s1 += __shfl_down(s1, off);
    s2 += __shfl_down(s2, off);
  }
  s1 = __shfl(s1, 0); s2 = __shfl(s2, 0);
  const float mean = s1 * (1.f / 128.f);
  const float var = s2 * (1.f / 128.f) - mean * mean;
  const float rs = rsqrtf(var + EPSV);
  const float o0 = (v0 - mean) * rs * w[lane] + bb[lane];
  const float o1 = (v1 - mean) * rs * w[lane + 64] + bb[lane + 64];
  out[row * 128 + lane] = o0;
  out[row * 128 + lane + 64] = o1;
  store_split(outs, row, lane, o0);
  store_split(outs, row, lane + 64, o1);
}

// ---------------------------------------------------------------------------
// Depthwise causal conv (DC=4) + SiLU; fp32 out (scan) + fused split (xproj A)
// ---------------------------------------------------------------------------
__global__ __launch_bounds__(256) void conv_silu_k(
    const float* __restrict__ xz, const float* __restrict__ cw,
    const float* __restrict__ cb, float* __restrict__ out,
    _Float16* __restrict__ outs)
{
  const int idx = blockIdx.x * 256 + threadIdx.x;
  const int di = idx & 1023;
  const int m = idx >> 10;
  const int t = m & (TT - 1);
  float acc = cb[di];
#pragma unroll
  for (int k = 0; k < 4; k++) {
    int tt = t + k - 3;
    if (tt >= 0) acc += xz[(size_t)(m + k - 3) * 2048 + di] * cw[di * 4 + k];
  }
  const float y = acc / (1.f + __expf(-acc));
  out[(size_t)m * 1024 + di] = y;
  store_split(outs, (size_t)m, di, y);
}

// ---------------------------------------------------------------------------
// Chunked selective scan, phase A: local scan, emit P=prod(dA), S=local h.
// ---------------------------------------------------------------------------
__global__ __launch_bounds__(64) void scan_partial_k(
    const float* __restrict__ dt,
    const float* __restrict__ dbc,
    const float* __restrict__ xi,
    const float* __restrict__ Alog,
    float* __restrict__ Pb, float* __restrict__ Sb)
{
  const int slice = blockIdx.x & 15;
  const int c = blockIdx.x >> 4;
  const int b = blockIdx.y;
  const int di = slice * 64 + threadIdx.x;

  float A[NSTATE];
#pragma unroll
  for (int n = 0; n < NSTATE; n++) A[n] = -__expf(Alog[di * NSTATE + n]);
  float h[NSTATE], P[NSTATE];
#pragma unroll
  for (int n = 0; n < NSTATE; n++) { h[n] = 0.f; P[n] = 1.f; }

  const size_t m0 = (size_t)b * TT + (size_t)c * CHUNK;
  for (int t = 0; t < CHUNK; t++) {
    const size_t m = m0 + t;
    const float dtv = dt[m * 1024 + di];
    const float xv  = xi[m * 1024 + di];
    const float dtx = dtv * xv;
#pragma unroll
    for (int n = 0; n < NSTATE; n++) {
      const float Bv = dbc[m * 64 + 32 + n];
      const float dA = __expf(dtv * A[n]);
      h[n] = h[n] * dA + dtx * Bv;
      P[n] *= dA;
    }
  }
  const size_t base = (((size_t)b * NCH + c) * NSTATE) * 1024 + di;
#pragma unroll
  for (int n = 0; n < NSTATE; n++) {
    Pb[base + (size_t)n * 1024] = P[n];
    Sb[base + (size_t)n * 1024] = h[n];
  }
}

// ---------------------------------------------------------------------------
// Phase B: sequential chunk fix-up per (b, di).
// ---------------------------------------------------------------------------
__global__ __launch_bounds__(256) void scan_fix_k(
    float* __restrict__ Pb, const float* __restrict__ Sb)
{
  const int idx = blockIdx.x * 256 + threadIdx.x;
  const int b = idx >> 10;
  const int di = idx & 1023;
  float h[NSTATE];
#pragma unroll
  for (int n = 0; n < NSTATE; n++) h[n] = 0.f;
  for (int c = 0; c < NCH; c++) {
    const size_t base = (((size_t)b * NCH + c) * NSTATE) * 1024 + di;
    float P[NSTATE], S[NSTATE];
#pragma unroll
    for (int n = 0; n < NSTATE; n++) {
      P[n] = Pb[base + (size_t)n * 1024];
      S[n] = Sb[base + (size_t)n * 1024];
    }
#pragma unroll
    for (int n = 0; n < NSTATE; n++) {
      Pb[base + (size_t)n * 1024] = h[n];
      h[n] = P[n] * h[n] + S[n];
    }
  }
}

// ---------------------------------------------------------------------------
// Phase C: re-run each chunk from h_in; y = dot(h,C) + D*x; *= silu(z).
// Writes SPLIT format (only consumer is outproj GEMM).
// ---------------------------------------------------------------------------
__global__ __launch_bounds__(64) void scan_final_k(
    const float* __restrict__ dt,
    const float* __restrict__ dbc,
    const float* __restrict__ xi,
    const float* __restrict__ xz,
    const float* __restrict__ Alog,
    const float* __restrict__ Dp,
    const float* __restrict__ Hin,
    _Float16* __restrict__ Y)
{
  const int slice = blockIdx.x & 15;
  const int c = blockIdx.x >> 4;
  const int b = blockIdx.y;
  const int di = slice * 64 + threadIdx.x;

  float A[NSTATE];
#pragma unroll
  for (int n = 0; n < NSTATE; n++) A[n] = -__expf(Alog[di * NSTATE + n]);
  const float Dv = Dp[di];
  float h[NSTATE];
  const size_t hbase = (((size_t)b * NCH + c) * NSTATE) * 1024 + di;
#pragma unroll
  for (int n = 0; n < NSTATE; n++) h[n] = Hin[hbase + (size_t)n * 1024];

  const size_t m0 = (size_t)b * TT + (size_t)c * CHUNK;
  for (int t = 0; t < CHUNK; t++) {
    const size_t m = m0 + t;
    const float dtv = dt[m * 1024 + di];
    const float xv  = xi[m * 1024 + di];
    const float zv  = xz[m * 2048 + 1024 + di];
    const float dtx = dtv * xv;
    float y = 0.f;
#pragma unroll
    for (int n = 0; n < NSTATE; n++) {
      const float Bv = dbc[m * 64 + 32 + n];
      const float Cv = dbc[m * 64 + 48 + n];
      const float dA = __expf(dtv * A[n]);
      h[n] = h[n] * dA + dtx * Bv;
      y += h[n] * Cv;
    }
    y += Dv * xv;
    y *= zv / (1.f + __expf(-zv));
    store_split(Y, m, di, y);
  }
}

// ---------------------------------------------------------------------------
extern "C" void kernel_launch(void* const* d_in, const int* in_sizes, int n_in,
                              void* d_out, int out_size, void* d_ws, size_t ws_size,
                              hipStream_t stream)
{
  (void)in_sizes; (void)n_in; (void)out_size; (void)ws_size;
  const float* emb      = (const float*)d_in[0];
  const float* t_wqkv   = (const float*)d_in[1];
  const float* t_bqkv   = (const float*)d_in[2];
  const float* t_wo     = (const float*)d_in[3];
  const float* t_bo     = (const float*)d_in[4];
  const float* t_ln1w   = (const float*)d_in[5];
  const float* t_ln1b   = (const float*)d_in[6];
  const float* t_w1     = (const float*)d_in[7];
  const float* t_b1     = (const float*)d_in[8];
  const float* t_w2     = (const float*)d_in[9];
  const float* t_b2     = (const float*)d_in[10];
  const float* t_ln2w   = (const float*)d_in[11];
  const float* t_ln2b   = (const float*)d_in[12];
  const float* w_in     = (const float*)d_in[13];
  const float* b_in     = (const float*)d_in[14];
  const float* m_inproj = (const float*)d_in[15];
  const float* m_convw  = (const float*)d_in[16];
  const float* m_convb  = (const float*)d_in[17];
  const float* m_xproj  = (const float*)d_in[18];
  const float* m_dtw    = (const float*)d_in[19];
  const float* m_dtb    = (const float*)d_in[20];
  const float* m_Alog   = (const float*)d_in[21];
  const float* m_D      = (const float*)d_in[22];
  const float* m_outproj= (const float*)d_in[23];
  const float* w_out    = (const float*)d_in[24];
  const float* b_out    = (const float*)d_in[25];

  // Workspace: EXACTLY the round-0 footprint (MM*6208 floats, 203.4 MB).
  float* ws = (float*)d_ws;
  float* R1 = ws;                         // MM*512   x fp32 | mamba xos/xcs
  float* R2 = ws + (size_t)MM * 512;      // MM*512   wo partials | w_in split | mamba xcs/xos
  float* R3 = ws + (size_t)MM * 1024;     // MM*2048  qkv | w1 split | xz | outproj partials
  float* R4 = ws + (size_t)MM * 3072;     // MM*1024  transformer weight splits | xi fp32
  float* R5 = ws + (size_t)MM * 4096;     // MM*1024  wo/w2 out fp32 | dt fp32
  float* R6 = ws + (size_t)MM * 5120;     // MM*1024  ASP1 + w2 partials | xi-split/DTA/Y-split
  float* R7 = ws + (size_t)MM * 6144;     // MM*64    dbc

  // transformer weight splits in R4 (each split elem = 4B, same as fp32)
  _Float16* TWQKV = (_Float16*)R4;                    // 6*384  x 128
  _Float16* TWO   = TWQKV + (size_t)294912 * 2;       // 6*128  x 128
  _Float16* TW1   = TWO   + (size_t)98304 * 2;        // 6*2048 x 128
  _Float16* TW2   = TW1   + (size_t)1572864 * 2;      // 6*128  x 2048
  _Float16* TWIN  = TW2   + (size_t)1572864 * 2;      // 512    x 128  (ends at MM*440)

  _Float16* ASP1 = (_Float16*)R6;                     // M x 128 split
  _Float16* XIS  = (_Float16*)R6;                     // M x 1024 split (mamba)
  _Float16* DTA  = (_Float16*)R6;                     // M x 32 split (overlays XIS head)
  _Float16* YSP  = (_Float16*)R6;                     // M x 1024 split (scan out)

  dim3 blk(256);
  auto split = [&](const float* src, int lda, int rows, int K, _Float16* dst) {
    hipLaunchKernelGGL(split_k, dim3(rows * (K / 32) / 256), blk, 0, stream,
                       src, lda, rows, dst);
  };
  auto gemm = [&](const _Float16* Ap, const _Float16* Wp, int wstr,
                  const float* bias, float* C, int N, int K, int act,
                  int S, float* P, _Float16* Cs, _Float16* dta, bool tn64) {
    dim3 g(N / (tn64 ? 64 : 128), MM / 128, S);
    if (tn64)
      hipLaunchKernelGGL(gemm_ps_t<64>, g, blk, 0, stream,
                         Ap, MM, Wp, wstr, bias, C, P, Cs, N, K, S, act);
    else
      hipLaunchKernelGGL(gemm_ps_t<128>, g, blk, 0, stream,
                         Ap, MM, Wp, wstr, bias, C, P, Cs, N, K, S, act);
    if (S > 1) {
      int stride4 = (int)((size_t)MM * N / 4);
      hipLaunchKernelGGL(reduce_k, dim3(stride4 / 256), blk, 0, stream,
                         P, bias, C, Cs, dta, N - 1, __builtin_ctz(N), S, act,
                         stride4);
    }
  };

  // ---- one-time splits (transformer weights + emb) ----
  split(t_wqkv, 128,  2304,  128, TWQKV);
  split(t_wo,   128,   768,  128, TWO);
  split(t_w1,   128, 12288,  128, TW1);
  split(t_w2,  2048,   768, 2048, TW2);
  split(w_in,   128,   512,  128, TWIN);
  split(emb,    128,    MM,  128, ASP1);

  // ---- transformer stack ----
  const float* x = emb;
  for (int l = 0; l < NTT; l++) {
    // qkv: N=384 K=128 (fp32 out -> attn)
    gemm(ASP1, TWQKV + (size_t)l * 384 * 64, 2304, t_bqkv + l * 384,
         R3, 384, 128, 0, 1, nullptr, nullptr, nullptr, false);
    // attention -> split ASP1 (wo's A)
    hipLaunchKernelGGL(attn_mfma_k, dim3(TT / 128, HB * 8), blk, 0, stream,
                       R3, ASP1);
    // wo: N=128 K=128, S=2, partials in R2
    gemm(ASP1, TWO + (size_t)l * 128 * 64, 768, t_bo + l * 128,
         R5, 128, 128, 0, 2, R2, nullptr, nullptr, true);
    hipLaunchKernelGGL(add_ln_k, dim3(MM / 4), blk, 0, stream,
                       x, R5, t_ln1w + l * 128, t_ln1b + l * 128, R1, ASP1);
    // w1: N=2048 K=128, relu, split-only output overlaid in R3 (w2's A)
    gemm(ASP1, TW1 + (size_t)l * 2048 * 64, 12288, t_b1 + l * 2048,
         R3, 2048, 128, 1, 1, nullptr, (_Float16*)R3, nullptr, false);
    // w2: N=128 K=2048, S=8, partials fill R6 (ASP1 dead here)
    gemm((_Float16*)R3, TW2 + (size_t)l * 128 * 64, 768, t_b2 + l * 128,
         R5, 128, 2048, 0, 8, R6, nullptr, nullptr, false);
    hipLaunchKernelGGL(add_ln_k, dim3(MM / 4), blk, 0, stream,
                       R1, R5, t_ln2w + l * 128, t_ln2b + l * 128, R1, ASP1);
    x = R1;
  }

  // w_in: N=512 K=128, split-only output -> R2 (mamba x)
  gemm(ASP1, TWIN, 512, b_in, R2, 512, 128, 0, 1, nullptr, (_Float16*)R2,
       nullptr, false);

  float* xcs = R2;
  float* xos = R1;
  for (int l = 0; l < NMM; l++) {
    // per-layer mamba weight splits into dead slivers of xos:
    //   inproj -> xos[MM*256 : MM*384), xproj -> [384:392), dtw -> [392:396)
    _Float16* WIs = (_Float16*)(xos + (size_t)MM * 256);
    _Float16* WXs = (_Float16*)(xos + (size_t)MM * 384);
    _Float16* WDs = (_Float16*)(xos + (size_t)MM * 392);
    _Float16* WOs = (_Float16*)(xos + (size_t)MM * 256);  // split after scan_fix
    hipLaunchKernelGGL(split3_k, dim3(140), blk, 0, stream,
        m_inproj + (size_t)l * 2048 * 512, 512, 2048, WIs, 128,
        m_xproj  + (size_t)l * 64 * 1024, 1024,   64, WXs,   8,
        m_dtw    + (size_t)l * 1024 * 32,   32, 1024, WDs);

    // inproj: N=2048 K=512, fp32 out (conv + z) -> R3
    gemm((_Float16*)xcs, WIs, 2048, nullptr,
         R3, 2048, 512, 0, 1, nullptr, nullptr, nullptr, false);
    hipLaunchKernelGGL(conv_silu_k, dim3(MM * 1024 / 256), blk, 0, stream,
                       R3, m_convw + (size_t)l * 1024 * 4, m_convb + l * 1024,
                       R4, XIS);
    // xproj: N=64 K=1024, S=4, partials xos[0:256); reduce also emits DTA
    gemm(XIS, WXs, 64, nullptr,
         R7, 64, 1024, 0, 4, xos, nullptr, DTA, true);
    // dtw: N=1024 K=32, softplus -> R5
    gemm(DTA, WDs, 1024, m_dtb + l * 1024,
         R5, 1024, 32, 2, 1, nullptr, nullptr, nullptr, false);

    float* Pb = xos;
    float* Sb = xos + (size_t)MM * 256;
    hipLaunchKernelGGL(scan_partial_k, dim3(16 * NCH, HB), dim3(64), 0, stream,
                       R5, R7, R4, m_Alog + (size_t)l * 1024 * 16, Pb, Sb);
    hipLaunchKernelGGL(scan_fix_k, dim3(MM / 1024 * 4), blk, 0, stream, Pb, Sb);
    // outproj weight split now (Sb dead, Pb still live for scan_final)
    split(m_outproj + (size_t)l * 512 * 1024, 1024, 512, 1024, WOs);
    hipLaunchKernelGGL(scan_final_k, dim3(16 * NCH, HB), dim3(64), 0, stream,
                       R5, R7, R4, R3,
                       m_Alog + (size_t)l * 1024 * 16, m_D + l * 1024, Pb, YSP);

    // outproj: N=512 K=1024, S=2, partials R3 (xz dead), split out -> xos
    gemm(YSP, WOs, 512, nullptr,
         R5, 512, 1024, 0, 2, R3, (_Float16*)xos, nullptr, false);
    float* ts = xcs; xcs = xos; xos = ts;
  }

  // w_out: N=128 K=512, S=4, partials in R6 (dead); weight split in xos (dead)
  _Float16* WOUTs = (_Float16*)xos;
  split(w_out, 512, 128, 512, WOUTs);
  gemm((_Float16*)xcs, WOUTs, 128, b_out,
       (float*)d_out, 128, 512, 0, 4, R6, nullptr, nullptr, false);
}